// Round 11
// baseline (176.435 us; speedup 1.0000x reference)
//
#include <hip/hip_runtime.h>
#include <math.h>

#define NB 8      // NUM_BATCHES
#define C  256    // channels
#define CR 64     // C / r

#define POOL_BLOCKS  512
#define SCALE_BLOCKS 2048
#define RM_BLOCKS    64     // reduce_mlp grid (all co-resident: 64 < 256 CUs)

typedef float vf4 __attribute__((ext_vector_type(4)));

// ---------------------------------------------------------------------------
// Kernel 1: per-batch partial sums + counts. One wave per 4-row group
// (4 KB contiguous NT streaming), SOFTWARE-PIPELINED (R10: -3.5us).
// Wave-uniform bid -> branch-free predicated FMA into vf4 acc[8] (VGPRs).
// Forward order + NT everywhere (R4/R8: cache-policy deviations lose ~10us).
// Block 0 also zeroes the reduce_mlp barrier counter (stream order + implicit
// dispatch-boundary release make it visible; avoids memset/init dispatches).
// ---------------------------------------------------------------------------
__global__ __launch_bounds__(256) void pool_kernel(
    const float* __restrict__ x,         // [N, 256]
    const int*   __restrict__ bids,      // [N]
    float*       __restrict__ partials,  // [POOL_BLOCKS][2048]
    float*       __restrict__ cpart,     // [POOL_BLOCKS][8]
    int*         __restrict__ ctl,       // [1] barrier counter for kernel 2
    int N)
{
    __shared__ float lsum[4][NB][C];   // 32 KB
    __shared__ float lcnt[4][NB];

    const int tid  = threadIdx.x;
    const int wid  = tid >> 6;
    const int lane = tid & 63;

    if (blockIdx.x == 0 && tid == 0) *ctl = 0;

    vf4   acc[NB];
    float cnt[NB];
    #pragma unroll
    for (int b = 0; b < NB; ++b) { acc[b] = (vf4){0.f,0.f,0.f,0.f}; cnt[b] = 0.f; }

    const int gwave   = blockIdx.x * 4 + wid;
    const int totw    = POOL_BLOCKS * 4;
    const int ngroups = N >> 2;

    int g = gwave;
    if (g < ngroups) {
        size_t r0 = (size_t)g * 4;
        int4 bb = *((const int4*)(bids + r0));
        vf4 v0 = __builtin_nontemporal_load(((const vf4*)(x + (r0 + 0) * C)) + lane);
        vf4 v1 = __builtin_nontemporal_load(((const vf4*)(x + (r0 + 1) * C)) + lane);
        vf4 v2 = __builtin_nontemporal_load(((const vf4*)(x + (r0 + 2) * C)) + lane);
        vf4 v3 = __builtin_nontemporal_load(((const vf4*)(x + (r0 + 3) * C)) + lane);
        while (true) {
            const int gn = g + totw;
            const bool more = (gn < ngroups);
            int4 nb; vf4 n0, n1, n2, n3;
            if (more) {                       // prefetch next group FIRST
                const size_t rn = (size_t)gn * 4;
                nb = *((const int4*)(bids + rn));
                n0 = __builtin_nontemporal_load(((const vf4*)(x + (rn + 0) * C)) + lane);
                n1 = __builtin_nontemporal_load(((const vf4*)(x + (rn + 1) * C)) + lane);
                n2 = __builtin_nontemporal_load(((const vf4*)(x + (rn + 2) * C)) + lane);
                n3 = __builtin_nontemporal_load(((const vf4*)(x + (rn + 3) * C)) + lane);
            }
            const int b0 = __builtin_amdgcn_readfirstlane(bb.x);
            const int b1 = __builtin_amdgcn_readfirstlane(bb.y);
            const int b2 = __builtin_amdgcn_readfirstlane(bb.z);
            const int b3 = __builtin_amdgcn_readfirstlane(bb.w);
            #pragma unroll
            for (int b = 0; b < NB; ++b) {
                const float m0 = (b0 == b) ? 1.f : 0.f;
                const float m1 = (b1 == b) ? 1.f : 0.f;
                const float m2 = (b2 == b) ? 1.f : 0.f;
                const float m3 = (b3 == b) ? 1.f : 0.f;
                acc[b] += v0 * m0;
                acc[b] += v1 * m1;
                acc[b] += v2 * m2;
                acc[b] += v3 * m3;
                cnt[b] += m0 + m1 + m2 + m3;
            }
            if (!more) break;
            bb = nb; v0 = n0; v1 = n1; v2 = n2; v3 = n3; g = gn;
        }
    }
    // leftover rows if N % 4 != 0 (none at N=262144) — wave 0 handles them
    if (gwave == 0) {
        for (int row = ngroups * 4; row < N; ++row) {
            const int bb = __builtin_amdgcn_readfirstlane(bids[row]);
            const vf4 v = ((const vf4*)(x + (size_t)row * C))[lane];
            #pragma unroll
            for (int b = 0; b < NB; ++b) {
                const float m = (bb == b) ? 1.f : 0.f;
                acc[b] += v * m;
                cnt[b] += m;
            }
        }
    }

    // one conflict-free b128 LDS write per batch per lane
    #pragma unroll
    for (int b = 0; b < NB; ++b)
        ((vf4*)&lsum[wid][b][0])[lane] = acc[b];
    if (lane == 0) {
        #pragma unroll
        for (int b = 0; b < NB; ++b) lcnt[wid][b] = cnt[b];
    }
    __syncthreads();

    float* pout = partials + (size_t)blockIdx.x * (NB * C);
    for (int i = tid; i < NB * C; i += 256)
        pout[i] = lsum[0][0][i] + lsum[1][0][i] + lsum[2][0][i] + lsum[3][0][i];
    if (tid < NB)
        cpart[blockIdx.x * NB + tid] =
            lcnt[0][tid] + lcnt[1][tid] + lcnt[2][tid] + lcnt[3][tid];
}

// ---------------------------------------------------------------------------
// Kernel 2 (fused reduce + MLP, 64 blocks):
//  Phase A: block owns 32 columns; 256 threads = 8 row-groups x 32 cols;
//           each thread sums 64 of the 512 partial rows (128B-coalesced),
//           LDS-merge -> gsums. Block 0 reduces counts -> gcnts.
//  software grid barrier (counter pre-zeroed by pool_kernel; 64 blocks are
//           trivially co-resident; R6 validated this barrier primitive).
//  Phase B: every block computes pooled+h redundantly (~0.5us of FMA), then
//           writes its own 32-element slice of y = sigmoid(h@W2+b2).
// Replaces reduce_kernel + 1-block mlp_kernel: one less dispatch gap, no
// partial2 round-trip, MLP 64-way parallel instead of 1 CU.
// ---------------------------------------------------------------------------
__global__ __launch_bounds__(256) void reduce_mlp_kernel(
    const float* __restrict__ partials,  // [POOL_BLOCKS][2048]
    const float* __restrict__ cpart,     // [POOL_BLOCKS][8]
    const float* __restrict__ W1,        // [256][64]
    const float* __restrict__ b1,        // [64]
    const float* __restrict__ W2,        // [64][256]
    const float* __restrict__ b2,        // [256]
    float*       __restrict__ gsums,     // [2048]
    float*       __restrict__ gcnts,     // [8]
    int*         __restrict__ ctl,       // [1] (zeroed by pool_kernel)
    float*       __restrict__ y)         // [8][256] out
{
    __shared__ float red[256];
    __shared__ float credbuf[64];
    __shared__ float pl[NB * C];
    __shared__ float h[NB * CR];
    __shared__ float cn[NB];

    const int tid = threadIdx.x;
    const int blk = blockIdx.x;

    // ---- phase A: column sums over all partial rows ----
    const int col = blk * 32 + (tid & 31);
    const int rg  = tid >> 5;                 // 0..7
    float s = 0.f;
    #pragma unroll 8
    for (int r = rg; r < POOL_BLOCKS; r += 8)
        s += partials[(size_t)r * (NB * C) + col];
    red[tid] = s;
    if (blk == 0 && tid < 64) {               // counts: b = tid&7, rseg = tid>>3
        const int b = tid & 7, rs = tid >> 3;
        float c = 0.f;
        for (int r = rs; r < POOL_BLOCKS; r += 8) c += cpart[r * NB + b];
        credbuf[tid] = c;
    }
    __syncthreads();
    if (rg == 0) {                            // tid = 0..31
        float t = 0.f;
        #pragma unroll
        for (int k = 0; k < 8; ++k) t += red[k * 32 + tid];
        gsums[blk * 32 + tid] = t;
    }
    if (blk == 0 && tid < NB) {
        float t = 0.f;
        #pragma unroll
        for (int k = 0; k < 8; ++k) t += credbuf[k * 8 + tid];
        gcnts[tid] = t;
    }

    // ---- grid barrier ----
    __syncthreads();
    if (tid == 0) {
        __threadfence();                       // release our gsums/gcnts
        atomicAdd(ctl, 1);
        while (__hip_atomic_load(ctl, __ATOMIC_RELAXED,
                                 __HIP_MEMORY_SCOPE_AGENT) < RM_BLOCKS)
            __builtin_amdgcn_s_sleep(8);
        __threadfence();                       // acquire others' writes
    }
    __syncthreads();

    // ---- phase B: redundant pooled + h; own y slice ----
    if (tid < NB) cn[tid] = fmaxf(gcnts[tid], 1.f);
    __syncthreads();
    for (int i = tid; i < NB * C; i += 256)
        pl[i] = gsums[i] / cn[i >> 8];
    __syncthreads();
    for (int o = tid; o < NB * CR; o += 256) {    // h: 2 outputs/thread
        const int b = o >> 6, j = o & 63;
        float a = b1[j];
        #pragma unroll 4
        for (int k = 0; k < C; ++k) a = fmaf(pl[b * C + k], W1[k * CR + j], a);
        h[o] = fmaxf(a, 0.f);
    }
    __syncthreads();
    if (tid < 32) {                               // y slice: 32 outputs/block
        const int o = blk * 32 + tid;
        const int b = o >> 8, j = o & 255;
        float a = b2[j];
        #pragma unroll
        for (int k = 0; k < CR; ++k) a = fmaf(h[b * CR + k], W2[k * C + j], a);
        y[o] = 1.f / (1.f + __expf(-a));
    }
}

// ---------------------------------------------------------------------------
// Kernel 3: out[row,:] = y[bids[row],:] * x[row,:]. One wave per 4-row group,
// SOFTWARE-PIPELINED (R10), FORWARD order, y in LDS (uniform bid -> 2-way
// b128 = free), NT load/store.
// ---------------------------------------------------------------------------
__global__ __launch_bounds__(256) void scale_kernel(
    const float* __restrict__ x,     // [N, 256]
    const int*   __restrict__ bids,  // [N]
    const float* __restrict__ y,     // [8][256]
    float*       __restrict__ out,   // [N, 256]
    int N)
{
    __shared__ float ly[NB][C];      // 8 KB
    const int tid = threadIdx.x;
    for (int i = tid; i < NB * C; i += 256) (&ly[0][0])[i] = y[i];
    __syncthreads();

    const int wid  = tid >> 6;
    const int lane = tid & 63;
    const int gwave   = blockIdx.x * 4 + wid;
    const int totw    = SCALE_BLOCKS * 4;
    const int ngroups = N >> 2;

    int g = gwave;
    if (g < ngroups) {
        size_t r0 = (size_t)g * 4;
        int4 bb = *((const int4*)(bids + r0));
        vf4 v0 = __builtin_nontemporal_load(((const vf4*)(x + (r0 + 0) * C)) + lane);
        vf4 v1 = __builtin_nontemporal_load(((const vf4*)(x + (r0 + 1) * C)) + lane);
        vf4 v2 = __builtin_nontemporal_load(((const vf4*)(x + (r0 + 2) * C)) + lane);
        vf4 v3 = __builtin_nontemporal_load(((const vf4*)(x + (r0 + 3) * C)) + lane);
        while (true) {
            const int gn = g + totw;
            const bool more = (gn < ngroups);
            int4 nb; vf4 n0, n1, n2, n3;
            if (more) {                       // prefetch next group FIRST
                const size_t rn = (size_t)gn * 4;
                nb = *((const int4*)(bids + rn));
                n0 = __builtin_nontemporal_load(((const vf4*)(x + (rn + 0) * C)) + lane);
                n1 = __builtin_nontemporal_load(((const vf4*)(x + (rn + 1) * C)) + lane);
                n2 = __builtin_nontemporal_load(((const vf4*)(x + (rn + 2) * C)) + lane);
                n3 = __builtin_nontemporal_load(((const vf4*)(x + (rn + 3) * C)) + lane);
            }
            const size_t r0c = (size_t)g * 4;
            const int b0 = __builtin_amdgcn_readfirstlane(bb.x);
            const int b1 = __builtin_amdgcn_readfirstlane(bb.y);
            const int b2 = __builtin_amdgcn_readfirstlane(bb.z);
            const int b3 = __builtin_amdgcn_readfirstlane(bb.w);
            const vf4 g0 = ((const vf4*)&ly[b0][0])[lane];
            const vf4 g1 = ((const vf4*)&ly[b1][0])[lane];
            const vf4 g2 = ((const vf4*)&ly[b2][0])[lane];
            const vf4 g3 = ((const vf4*)&ly[b3][0])[lane];
            __builtin_nontemporal_store(v0 * g0, ((vf4*)(out + (r0c + 0) * C)) + lane);
            __builtin_nontemporal_store(v1 * g1, ((vf4*)(out + (r0c + 1) * C)) + lane);
            __builtin_nontemporal_store(v2 * g2, ((vf4*)(out + (r0c + 2) * C)) + lane);
            __builtin_nontemporal_store(v3 * g3, ((vf4*)(out + (r0c + 3) * C)) + lane);
            if (!more) break;
            bb = nb; v0 = n0; v1 = n1; v2 = n2; v3 = n3; g = gn;
        }
    }
    if (gwave == 0) {                 // tail rows if N % 4 != 0
        for (int row = ngroups * 4; row < N; ++row) {
            const int bb = __builtin_amdgcn_readfirstlane(bids[row]);
            const vf4 v  = ((const vf4*)(x + (size_t)row * C))[lane];
            const vf4 gg = ((const vf4*)&ly[bb][0])[lane];
            ((vf4*)(out + (size_t)row * C))[lane] = v * gg;
        }
    }
}

extern "C" void kernel_launch(void* const* d_in, const int* in_sizes, int n_in,
                              void* d_out, int out_size, void* d_ws, size_t ws_size,
                              hipStream_t stream)
{
    const float* x    = (const float*)d_in[0];
    const int*   bids = (const int*)  d_in[1];
    const float* W1   = (const float*)d_in[2];
    const float* b1   = (const float*)d_in[3];
    const float* W2   = (const float*)d_in[4];
    const float* b2   = (const float*)d_in[5];
    float* out = (float*)d_out;

    const int N = in_sizes[1];           // 262144

    // ws layout (floats), all regions fully written before read each call:
    // partials[512*2048] | cpart[512*8] | gsums[2048] | gcnts[8] | ctl[8] | gy[2048]
    float* partials = (float*)d_ws;
    float* cpart    = partials + POOL_BLOCKS * (NB * C);
    float* gsums    = cpart + POOL_BLOCKS * NB;
    float* gcnts    = gsums + NB * C;
    int*   ctl      = (int*)(gcnts + NB);
    float* gy       = gcnts + NB + 8;

    pool_kernel      <<<POOL_BLOCKS, 256, 0, stream>>>(x, bids, partials, cpart, ctl, N);
    reduce_mlp_kernel<<<RM_BLOCKS, 256, 0, stream>>>(partials, cpart, W1, b1, W2, b2,
                                                     gsums, gcnts, ctl, gy);
    scale_kernel     <<<SCALE_BLOCKS, 256, 0, stream>>>(x, bids, gy, out, N);
}

// Round 12
// 164.202 us; speedup vs baseline: 1.0745x; 1.0745x over previous
//
#include <hip/hip_runtime.h>
#include <math.h>

#define NB 8      // NUM_BATCHES
#define C  256    // channels
#define CR 64     // C / r

#define POOL_BLOCKS  512
#define SCALE_BLOCKS 2048

typedef float vf4 __attribute__((ext_vector_type(4)));

// ---------------------------------------------------------------------------
// Kernel 1: per-batch partial sums + counts. One wave per 4-row group
// (4 KB contiguous NT streaming), SOFTWARE-PIPELINED depth-1 (R10: -3.5us).
// Wave-uniform bid -> branch-free predicated FMA into vf4 acc[8] (VGPRs).
// Forward order + NT everywhere (R4/R8: cache-policy deviations lose ~10us).
// ---------------------------------------------------------------------------
__global__ __launch_bounds__(256) void pool_kernel(
    const float* __restrict__ x,         // [N, 256]
    const int*   __restrict__ bids,      // [N]
    float*       __restrict__ partials,  // [POOL_BLOCKS][2048]
    float*       __restrict__ cpart,     // [POOL_BLOCKS][8]
    int N)
{
    __shared__ float lsum[4][NB][C];   // 32 KB
    __shared__ float lcnt[4][NB];

    const int tid  = threadIdx.x;
    const int wid  = tid >> 6;
    const int lane = tid & 63;

    vf4   acc[NB];
    float cnt[NB];
    #pragma unroll
    for (int b = 0; b < NB; ++b) { acc[b] = (vf4){0.f,0.f,0.f,0.f}; cnt[b] = 0.f; }

    const int gwave   = blockIdx.x * 4 + wid;
    const int totw    = POOL_BLOCKS * 4;
    const int ngroups = N >> 2;

    int g = gwave;
    if (g < ngroups) {
        size_t r0 = (size_t)g * 4;
        int4 bb = *((const int4*)(bids + r0));
        vf4 v0 = __builtin_nontemporal_load(((const vf4*)(x + (r0 + 0) * C)) + lane);
        vf4 v1 = __builtin_nontemporal_load(((const vf4*)(x + (r0 + 1) * C)) + lane);
        vf4 v2 = __builtin_nontemporal_load(((const vf4*)(x + (r0 + 2) * C)) + lane);
        vf4 v3 = __builtin_nontemporal_load(((const vf4*)(x + (r0 + 3) * C)) + lane);
        while (true) {
            const int gn = g + totw;
            const bool more = (gn < ngroups);
            int4 nb; vf4 n0, n1, n2, n3;
            if (more) {                       // prefetch next group FIRST
                const size_t rn = (size_t)gn * 4;
                nb = *((const int4*)(bids + rn));
                n0 = __builtin_nontemporal_load(((const vf4*)(x + (rn + 0) * C)) + lane);
                n1 = __builtin_nontemporal_load(((const vf4*)(x + (rn + 1) * C)) + lane);
                n2 = __builtin_nontemporal_load(((const vf4*)(x + (rn + 2) * C)) + lane);
                n3 = __builtin_nontemporal_load(((const vf4*)(x + (rn + 3) * C)) + lane);
            }
            const int b0 = __builtin_amdgcn_readfirstlane(bb.x);
            const int b1 = __builtin_amdgcn_readfirstlane(bb.y);
            const int b2 = __builtin_amdgcn_readfirstlane(bb.z);
            const int b3 = __builtin_amdgcn_readfirstlane(bb.w);
            #pragma unroll
            for (int b = 0; b < NB; ++b) {
                const float m0 = (b0 == b) ? 1.f : 0.f;
                const float m1 = (b1 == b) ? 1.f : 0.f;
                const float m2 = (b2 == b) ? 1.f : 0.f;
                const float m3 = (b3 == b) ? 1.f : 0.f;
                acc[b] += v0 * m0;
                acc[b] += v1 * m1;
                acc[b] += v2 * m2;
                acc[b] += v3 * m3;
                cnt[b] += m0 + m1 + m2 + m3;
            }
            if (!more) break;
            bb = nb; v0 = n0; v1 = n1; v2 = n2; v3 = n3; g = gn;
        }
    }
    // leftover rows if N % 4 != 0 (none at N=262144) — wave 0 handles them
    if (gwave == 0) {
        for (int row = ngroups * 4; row < N; ++row) {
            const int bb = __builtin_amdgcn_readfirstlane(bids[row]);
            const vf4 v = ((const vf4*)(x + (size_t)row * C))[lane];
            #pragma unroll
            for (int b = 0; b < NB; ++b) {
                const float m = (bb == b) ? 1.f : 0.f;
                acc[b] += v * m;
                cnt[b] += m;
            }
        }
    }

    // one conflict-free b128 LDS write per batch per lane
    #pragma unroll
    for (int b = 0; b < NB; ++b)
        ((vf4*)&lsum[wid][b][0])[lane] = acc[b];
    if (lane == 0) {
        #pragma unroll
        for (int b = 0; b < NB; ++b) lcnt[wid][b] = cnt[b];
    }
    __syncthreads();

    float* pout = partials + (size_t)blockIdx.x * (NB * C);
    for (int i = tid; i < NB * C; i += 256)
        pout[i] = lsum[0][0][i] + lsum[1][0][i] + lsum[2][0][i] + lsum[3][0][i];
    if (tid < NB)
        cpart[blockIdx.x * NB + tid] =
            lcnt[0][tid] + lcnt[1][tid] + lcnt[2][tid] + lcnt[3][tid];
}

// ---------------------------------------------------------------------------
// Kernel 2: tree-reduce the per-block partials. 64 blocks: blockIdx = jp*8+jo;
// block sums PR partial rows over its 256-col chunk (coalesced 1 KB reads).
// jo==0 blocks also reduce the count partials. (R9/R11: fusions regress.)
// ---------------------------------------------------------------------------
__global__ __launch_bounds__(256) void reduce_kernel(
    const float* __restrict__ partials,  // [POOL_BLOCKS][2048]
    const float* __restrict__ cpart,     // [POOL_BLOCKS][8]
    float*       __restrict__ partial2,  // [8][2048]
    float*       __restrict__ c2)        // [8][8]
{
    const int jo  = blockIdx.x & 7;   // column chunk
    const int jp  = blockIdx.x >> 3;  // partial-row chunk
    const int col = jo * 256 + threadIdx.x;
    const int PR  = POOL_BLOCKS / 8;  // 64 rows per jp

    float s = 0.f;
    #pragma unroll 8
    for (int p = 0; p < PR; ++p)
        s += partials[(size_t)(jp * PR + p) * (NB * C) + col];
    partial2[jp * (NB * C) + col] = s;

    if (jo == 0 && threadIdx.x < NB) {
        float c = 0.f;
        for (int p = 0; p < PR; ++p)
            c += cpart[(jp * PR + p) * NB + threadIdx.x];
        c2[jp * NB + threadIdx.x] = c;
    }
}

// ---------------------------------------------------------------------------
// Kernel 3: final reduce + tiny MLP. pooled = sums/max(cnt,1);
// h = relu(pooled@W1+b1); y = sigmoid(h@W2+b2). One block, 256 threads.
// ---------------------------------------------------------------------------
__global__ __launch_bounds__(256) void mlp_kernel(
    const float* __restrict__ partial2,  // [8][2048]
    const float* __restrict__ c2,        // [8][8]
    const float* __restrict__ W1,        // [256][64]
    const float* __restrict__ b1,        // [64]
    const float* __restrict__ W2,        // [64][256]
    const float* __restrict__ b2,        // [256]
    float*       __restrict__ y)         // [8][256] out
{
    __shared__ float pooled[NB][C];
    __shared__ float h[NB][CR];
    __shared__ float cnts[NB];
    const int tid = threadIdx.x;

    if (tid < NB) {
        float c = 0.f;
        #pragma unroll
        for (int j = 0; j < 8; ++j) c += c2[j * NB + tid];
        cnts[tid] = fmaxf(c, 1.f);
    }
    __syncthreads();

    for (int i = tid; i < NB * C; i += 256) {
        float s = 0.f;
        #pragma unroll
        for (int j = 0; j < 8; ++j) s += partial2[j * (NB * C) + i];
        (&pooled[0][0])[i] = s / cnts[i >> 8];
    }
    __syncthreads();

    // h: 8*64 = 512 outputs, 2 per thread
    for (int o = tid; o < NB * CR; o += 256) {
        const int b = o >> 6, j = o & 63;
        float acc = b1[j];
        #pragma unroll 4
        for (int k = 0; k < C; ++k) acc = fmaf(pooled[b][k], W1[k * CR + j], acc);
        (&h[0][0])[o] = fmaxf(acc, 0.f);
    }
    __syncthreads();

    // y: 8*256 = 2048 outputs, 8 per thread
    for (int o = tid; o < NB * C; o += 256) {
        const int b = o >> 8, j = o & 255;
        float acc = b2[j];
        #pragma unroll
        for (int k = 0; k < CR; ++k) acc = fmaf(h[b][k], W2[k * C + j], acc);
        y[o] = 1.f / (1.f + __expf(-acc));
    }
}

// ---------------------------------------------------------------------------
// Kernel 4: out[row,:] = y[bids[row],:] * x[row,:]. One wave per 4-row group,
// DEPTH-2 SOFTWARE PIPELINE: groups gA (processing), gB, gC (in flight) ->
// 8 vf4 loads outstanding per wave; each load gets ~2 iterations to land
// before its use. FORWARD order, y in LDS (uniform bid -> 2-way b128 = free),
// NT load/store.
// ---------------------------------------------------------------------------
#define LOADG(GG, BB, V0, V1, V2, V3)                                          \
    {                                                                          \
        const size_t rr = (size_t)(GG) * 4;                                    \
        BB = *((const int4*)(bids + rr));                                      \
        V0 = __builtin_nontemporal_load(((const vf4*)(x + (rr + 0) * C)) + lane); \
        V1 = __builtin_nontemporal_load(((const vf4*)(x + (rr + 1) * C)) + lane); \
        V2 = __builtin_nontemporal_load(((const vf4*)(x + (rr + 2) * C)) + lane); \
        V3 = __builtin_nontemporal_load(((const vf4*)(x + (rr + 3) * C)) + lane); \
    }

__global__ __launch_bounds__(256) void scale_kernel(
    const float* __restrict__ x,     // [N, 256]
    const int*   __restrict__ bids,  // [N]
    const float* __restrict__ y,     // [8][256]
    float*       __restrict__ out,   // [N, 256]
    int N)
{
    __shared__ float ly[NB][C];      // 8 KB
    const int tid = threadIdx.x;
    for (int i = tid; i < NB * C; i += 256) (&ly[0][0])[i] = y[i];
    __syncthreads();

    const int wid  = tid >> 6;
    const int lane = tid & 63;
    const int gwave   = blockIdx.x * 4 + wid;
    const int totw    = SCALE_BLOCKS * 4;
    const int ngroups = N >> 2;

    int gA = gwave;
    if (gA < ngroups) {
        int4 ab; vf4 a0, a1, a2, a3;
        LOADG(gA, ab, a0, a1, a2, a3);
        int  gB = gA + totw;
        bool hB = (gB < ngroups);
        int4 bbq; vf4 q0, q1, q2, q3;
        if (hB) LOADG(gB, bbq, q0, q1, q2, q3);
        while (true) {
            const int  gC = gB + totw;                 // valid only if hB
            const bool hC = hB && (gC < ngroups);
            int4 cb; vf4 c0, c1, c2, c3;
            if (hC) LOADG(gC, cb, c0, c1, c2, c3);
            // process group gA
            {
                const size_t r0 = (size_t)gA * 4;
                const int e0 = __builtin_amdgcn_readfirstlane(ab.x);
                const int e1 = __builtin_amdgcn_readfirstlane(ab.y);
                const int e2 = __builtin_amdgcn_readfirstlane(ab.z);
                const int e3 = __builtin_amdgcn_readfirstlane(ab.w);
                const vf4 g0 = ((const vf4*)&ly[e0][0])[lane];
                const vf4 g1 = ((const vf4*)&ly[e1][0])[lane];
                const vf4 g2 = ((const vf4*)&ly[e2][0])[lane];
                const vf4 g3 = ((const vf4*)&ly[e3][0])[lane];
                __builtin_nontemporal_store(a0 * g0, ((vf4*)(out + (r0 + 0) * C)) + lane);
                __builtin_nontemporal_store(a1 * g1, ((vf4*)(out + (r0 + 1) * C)) + lane);
                __builtin_nontemporal_store(a2 * g2, ((vf4*)(out + (r0 + 2) * C)) + lane);
                __builtin_nontemporal_store(a3 * g3, ((vf4*)(out + (r0 + 3) * C)) + lane);
            }
            if (!hB) break;
            gA = gB; ab = bbq; a0 = q0; a1 = q1; a2 = q2; a3 = q3;
            gB = gC; bbq = cb; q0 = c0; q1 = c1; q2 = c2; q3 = c3; hB = hC;
        }
    }
    if (gwave == 0) {                 // tail rows if N % 4 != 0
        for (int row = ngroups * 4; row < N; ++row) {
            const int bb = __builtin_amdgcn_readfirstlane(bids[row]);
            const vf4 v  = ((const vf4*)(x + (size_t)row * C))[lane];
            const vf4 gg = ((const vf4*)&ly[bb][0])[lane];
            ((vf4*)(out + (size_t)row * C))[lane] = v * gg;
        }
    }
}

extern "C" void kernel_launch(void* const* d_in, const int* in_sizes, int n_in,
                              void* d_out, int out_size, void* d_ws, size_t ws_size,
                              hipStream_t stream)
{
    const float* x    = (const float*)d_in[0];
    const int*   bids = (const int*)  d_in[1];
    const float* W1   = (const float*)d_in[2];
    const float* b1   = (const float*)d_in[3];
    const float* W2   = (const float*)d_in[4];
    const float* b2   = (const float*)d_in[5];
    float* out = (float*)d_out;

    const int N = in_sizes[1];           // 262144

    // ws layout (floats), all regions fully written before read each call:
    // partials[512*2048] | cpart[512*8] | partial2[8*2048] | c2[64] | gy[2048]
    float* partials = (float*)d_ws;
    float* cpart    = partials + POOL_BLOCKS * (NB * C);
    float* partial2 = cpart + POOL_BLOCKS * NB;
    float* c2       = partial2 + 8 * (NB * C);
    float* gy       = c2 + 64;

    pool_kernel  <<<POOL_BLOCKS, 256, 0, stream>>>(x, bids, partials, cpart, N);
    reduce_kernel<<<64, 256, 0, stream>>>(partials, cpart, partial2, c2);
    mlp_kernel   <<<1, 256, 0, stream>>>(partial2, c2, W1, b1, W2, b2, gy);
    scale_kernel <<<SCALE_BLOCKS, 256, 0, stream>>>(x, bids, gy, out, N);
}